// Round 3
// baseline (327.239 us; speedup 1.0000x reference)
//
#include <hip/hip_runtime.h>
#include <math.h>

#define B_   16
#define O_   1024
#define M_   64
#define C_   32
#define INO  16
#define INA  8
#define SLOPE 0.2f

// Accumulator field layout per column (col = (br*B_+b)*M_+m):
// [0]=l_in, [1..8]=ai, [9..24]=aoi, [25]=l_out, [26..33]=sao, [34..49]=aoo
#define NF    50
#define NFH   25          // fields per half (IN waves: 0..24, OUT waves: 25..49)
#define NCOL  (2*B_*M_)   // 2048 columns

// workspace layout (float offsets)
#define WS_EOPE   0
#define WS_ENODE  (WS_EOPE + B_*O_)              // 16384
#define WS_PNODE  (WS_ENODE + 2*B_*M_)           // 18432
#define WS_WARC   (WS_PNODE + 2*B_*M_*C_)        // 83968
#define WS_ACC    (WS_WARC + 16)                 // 83984  (NF*NCOL = 102400 floats)

// ---------------- kernel 0: tiny precompute + ACC zeroing ----------------
__global__ void k_pre(const float* __restrict__ feat_opes,
                      const float* __restrict__ feat_mas,
                      const float* __restrict__ feat_buf,
                      const float* __restrict__ W_ope,
                      const float* __restrict__ W_mas,
                      const float* __restrict__ W_buf,
                      const float* __restrict__ W_arc_in,
                      const float* __restrict__ W_arc_out,
                      const float* __restrict__ attn_ope,
                      const float* __restrict__ attn_mas,
                      const float* __restrict__ attn_arc,
                      float* __restrict__ ws) {
    int tid = threadIdx.x;
    int bid = blockIdx.x;
    if (bid < 64) {
        // e_ope[b,o] = feat_opes[b,o,:] . (W_ope @ attn_ope)
        __shared__ float wo[INO];
        if (tid < INO) {
            float s = 0.f;
            for (int c = 0; c < C_; ++c) s += W_ope[tid*C_ + c]*attn_ope[c];
            wo[tid] = s;
        }
        __syncthreads();
        int idx = bid*256 + tid;                 // [0, 16384)
        const float* f = feat_opes + idx*INO;
        float s = 0.f;
#pragma unroll
        for (int j = 0; j < INO; ++j) s += f[j]*wo[j];
        ws[WS_EOPE + idx] = s;
    } else if (bid < 72) {
        // p_node / e_node for both branches
        int idx = (bid - 64)*256 + tid;          // [0, 2048)
        int br  = idx >> 10;
        int rem = idx & 1023;
        const float* f = (br == 0 ? feat_mas : feat_buf) + rem*INA;
        const float* W = (br == 0 ? W_mas : W_buf);
        float f8[INA];
#pragma unroll
        for (int k = 0; k < INA; ++k) f8[k] = f[k];
        float e = 0.f;
        float* pn = ws + WS_PNODE + idx*C_;
        for (int c = 0; c < C_; ++c) {
            float s = 0.f;
#pragma unroll
            for (int k = 0; k < INA; ++k) s += f8[k]*W[k*C_ + c];
            pn[c] = s;
            e += s*attn_mas[c];
        }
        ws[WS_ENODE + idx] = e;
    } else if (bid == 72) {
        // w_arc_in/out 8-vectors: W_arc @ attn_arc
        if (tid < 16) {
            const float* W = (tid < 8) ? W_arc_in : W_arc_out;
            int k = tid & 7;
            float s = 0.f;
            for (int c = 0; c < C_; ++c) s += W[k*C_ + c]*attn_arc[c];
            ws[WS_WARC + tid] = s;
        }
    } else {
        // zero the atomic accumulator region (NF*NCOL = 102400 floats, 400 blocks)
        int idx = (bid - 73)*256 + tid;
        ws[WS_ACC + idx] = 0.f;
    }
}

// ---------------- kernel A: main streaming pass ----------------
// 512 threads = 8 waves: waves 0-3 process the IN stream (8 o's each),
// waves 4-7 the OUT stream for the same 32 o's. One stream per wave halves
// the per-iteration dependent chain and the accumulator register footprint.
__global__ __launch_bounds__(512, 6) void k_main(
        const float* __restrict__ adj0, const float* __restrict__ adj1,
        const float* __restrict__ adj2, const float* __restrict__ adj3,
        const float* __restrict__ feat_opes,
        const float* __restrict__ fin_ma,  const float* __restrict__ fin_buf,
        const float* __restrict__ fout_ma, const float* __restrict__ fout_buf,
        const float* __restrict__ ws_ro,   // read-only precompute region
        float* __restrict__ acc) {         // atomic accumulator region
    int tid = threadIdx.x;
    int m  = tid & 63;
    int w  = tid >> 6;          // 0..7
    int wl = w & 3;
    bool isOut = (w >= 4);
    int bid = blockIdx.x;
    int chunk = bid & 31;
    int t = bid >> 5;
    int b  = t & (B_ - 1);
    int br = t >> 4;
    int o0 = chunk*32 + wl*8;   // this wave: o in [o0, o0+8)

    const float* A = isOut ? (br ? adj3 : adj1) : (br ? adj2 : adj0);
    const float* F = isOut ? (br ? fout_buf : fout_ma) : (br ? fin_buf : fin_ma);

    // wave-uniform weight vector (8 SGPRs)
    const float* wvp = ws_ro + WS_WARC + (isOut ? 8 : 0);
    float w0=wvp[0],w1=wvp[1],w2=wvp[2],w3=wvp[3];
    float w4=wvp[4],w5=wvp[5],w6=wvp[6],w7=wvp[7];

    float e_node_m = ws_ro[WS_ENODE + (br*B_ + b)*M_ + m];

    // wave-uniform e_ope (8 SGPRs)
    const float* eop = ws_ro + WS_EOPE + b*O_ + o0;
    float eo[8];
#pragma unroll
    for (int i = 0; i < 8; ++i) eo[i] = eop[i];

    // per-lane adjacency flags
    const float* Ap = A + o0*M_ + m;
    float av[8];
#pragma unroll
    for (int i = 0; i < 8; ++i) av[i] = Ap[i*M_];

    const float* P = F + ((size_t)(b*O_ + o0)*M_ + m)*INA;
    const int OSTR = M_*INA;    // 512 floats per o

    const float* fo = feat_opes + (size_t)(b*O_ + o0)*INO;  // wave-uniform rows

    float acc_l = 0.f;
    float a8[8];                 // IN: ai (weighted arc);  OUT: sao (raw sum)
    float a16[16];               // IN: aoi;                OUT: aoo
#pragma unroll
    for (int k = 0; k < 8; ++k)  a8[k] = 0.f;
#pragma unroll
    for (int j = 0; j < 16; ++j) a16[j] = 0.f;

#pragma unroll
    for (int it = 0; it < 8; ++it) {
        float4 x0 = *(const float4*)(P + it*OSTR);
        float4 x1 = *(const float4*)(P + it*OSTR + 4);
        float d = x0.x*w0 + x0.y*w1 + x0.z*w2 + x0.w*w3
                + x1.x*w4 + x1.y*w5 + x1.z*w6 + x1.w*w7;
        float s = eo[it] + e_node_m + d;
        s = s > 0.f ? s : SLOPE*s;
        // scores are bounded for this data -> plain exp, no max-subtraction
        float we = (av[it] == 1.0f) ? __expf(s) : 0.f;
        acc_l += we;
        if (isOut) {
            a8[0] += x0.x; a8[1] += x0.y; a8[2] += x0.z; a8[3] += x0.w;
            a8[4] += x1.x; a8[5] += x1.y; a8[6] += x1.z; a8[7] += x1.w;
        } else {
            a8[0] += we*x0.x; a8[1] += we*x0.y; a8[2] += we*x0.z; a8[3] += we*x0.w;
            a8[4] += we*x1.x; a8[5] += we*x1.y; a8[6] += we*x1.z; a8[7] += we*x1.w;
        }
        const float* fr = fo + it*INO;   // 16 wave-uniform floats (s_loads)
#pragma unroll
        for (int j = 0; j < 16; ++j) a16[j] += we*fr[j];
    }

    // pack the 25-field half-state
    float v[NFH];
    v[0] = acc_l;
#pragma unroll
    for (int k = 0; k < 8; ++k)  v[1+k] = a8[k];
#pragma unroll
    for (int j = 0; j < 16; ++j) v[9+j] = a16[j];

    // intra-block reduction: waves {1,2,3} -> wave 0 (IN), {5,6,7} -> wave 4 (OUT)
    __shared__ float red[2][3][NFH][64];
    int part = isOut ? 1 : 0;
    if (wl > 0) {
#pragma unroll
        for (int f = 0; f < NFH; ++f) red[part][wl-1][f][m] = v[f];
    }
    __syncthreads();
    if (wl == 0) {
#pragma unroll
        for (int f = 0; f < NFH; ++f)
            v[f] += red[part][0][f][m] + red[part][1][f][m] + red[part][2][f][m];
        int col = (br*B_ + b)*M_ + m;
        int fb  = isOut ? NFH : 0;
#pragma unroll
        for (int f = 0; f < NFH; ++f)
            unsafeAtomicAdd(acc + (fb + f)*NCOL + col, v[f]);
    }
}

// ---------------- kernel B: epilogue ----------------
__global__ __launch_bounds__(64) void k_fin(
        const float* __restrict__ W_ope,
        const float* __restrict__ W_arc_in,
        const float* __restrict__ W_arc_out,
        const float* __restrict__ ws,
        float* __restrict__ out) {
    int m = threadIdx.x;         // [0,64)
    int bid = blockIdx.x;        // [0,32)
    int b  = bid & (B_ - 1);
    int br = bid >> 4;
    int col = (br*B_ + b)*M_ + m;

    __shared__ float sW[1024];   // [0..511]=W_ope, [512..767]=W_arc_in, [768..1023]=W_arc_out
    for (int i = m; i < 512; i += 64) sW[i] = W_ope[i];
    for (int i = m; i < 256; i += 64) { sW[512 + i] = W_arc_in[i]; sW[768 + i] = W_arc_out[i]; }
    __syncthreads();

    // batched coalesced read of the 50 accumulator fields
    const float* acc = ws + WS_ACC;
    float v[NF];
#pragma unroll
    for (int f = 0; f < NF; ++f) v[f] = acc[f*NCOL + col];

    // preload p_node row
    const float* pn = ws + WS_PNODE + col*C_;
    float pc[C_];
#pragma unroll
    for (int q = 0; q < 8; ++q) {
        float4 p4 = *(const float4*)(pn + 4*q);
        pc[4*q] = p4.x; pc[4*q+1] = p4.y; pc[4*q+2] = p4.z; pc[4*q+3] = p4.w;
    }

    // self (kk) entry
    float en  = ws[WS_ENODE + col];
    float ekk = 2.f*en; ekk = ekk > 0.f ? ekk : SLOPE*ekk;
    float wkk = __expf(ekk);

    float inv_i = 1.f / (v[0]  + wkk);   // l_in  + kk
    float inv_o = 1.f / (v[25] + wkk);   // l_out + kk
    float akk   = wkk*inv_i + wkk*inv_o;

    float* op = out + (size_t)col*C_;
#pragma unroll 4
    for (int c = 0; c < C_; ++c) {
        float s_ai = 0.f, s_oi = 0.f, s_ao = 0.f, s_oo = 0.f;
#pragma unroll
        for (int k = 0; k < 8; ++k) {
            s_ai += v[1+k] *sW[512 + k*C_ + c];   // ai  @ W_arc_in
            s_ao += v[26+k]*sW[768 + k*C_ + c];   // sao @ W_arc_out
        }
#pragma unroll
        for (int j = 0; j < 16; ++j) {
            float wv = sW[j*C_ + c];
            s_oi += v[9+j] *wv;                   // aoi @ W_ope
            s_oo += v[34+j]*wv;                   // aoo @ W_ope
        }
        float x = (s_ai + s_oi)*inv_i + s_ao + s_oo*inv_o + pc[c]*akk;
        op[c] = 1.f/(1.f + __expf(-x));
    }
}

extern "C" void kernel_launch(void* const* d_in, const int* in_sizes, int n_in,
                              void* d_out, int out_size, void* d_ws, size_t ws_size,
                              hipStream_t stream) {
    const float* adj0 = (const float*)d_in[0];
    const float* adj1 = (const float*)d_in[1];
    const float* adj2 = (const float*)d_in[2];
    const float* adj3 = (const float*)d_in[3];
    // d_in[4] = batch_idxes (unused by the reference)
    const float* feat_opes       = (const float*)d_in[5];
    const float* feat_mas        = (const float*)d_in[6];
    const float* feat_buf        = (const float*)d_in[7];
    const float* feat_arc_ma_in  = (const float*)d_in[8];
    const float* feat_arc_buf_in = (const float*)d_in[9];
    const float* feat_arc_ma_out = (const float*)d_in[10];
    const float* feat_arc_buf_out= (const float*)d_in[11];
    const float* W_ope    = (const float*)d_in[12];
    const float* W_mas    = (const float*)d_in[13];
    const float* W_buf    = (const float*)d_in[14];
    const float* W_arc_in = (const float*)d_in[15];
    const float* W_arc_out= (const float*)d_in[16];
    const float* attn_ope = (const float*)d_in[17];
    const float* attn_mas = (const float*)d_in[18];
    const float* attn_arc = (const float*)d_in[19];

    float* ws  = (float*)d_ws;
    float* out = (float*)d_out;

    // 73 precompute blocks + 400 blocks zeroing the ACC region
    k_pre<<<473, 256, 0, stream>>>(feat_opes, feat_mas, feat_buf,
                                   W_ope, W_mas, W_buf, W_arc_in, W_arc_out,
                                   attn_ope, attn_mas, attn_arc, ws);

    // 1024 blocks x 512 threads; each block: 32 o's, IN waves + OUT waves
    k_main<<<2*B_*32, 512, 0, stream>>>(adj0, adj1, adj2, adj3, feat_opes,
                                        feat_arc_ma_in, feat_arc_buf_in,
                                        feat_arc_ma_out, feat_arc_buf_out,
                                        ws, ws + WS_ACC);

    k_fin<<<2*B_, 64, 0, stream>>>(W_ope, W_arc_in, W_arc_out, ws, out);
}

// Round 4
// 240.665 us; speedup vs baseline: 1.3597x; 1.3597x over previous
//
#include <hip/hip_runtime.h>
#include <math.h>

#define B_   16
#define O_   1024
#define M_   64
#define C_   32
#define INO  16
#define INA  8
#define SLOPE 0.2f

// Accumulator field layout per column (col = (br*B_+b)*M_+m):
// IN  half: [0]=l_in,  [1..8]=ai,  [9..24]=aoi
// OUT half: [25]=l_out,[26..33]=sao,[34..49]=aoo
#define NF    50
#define NFH   25
#define NCOL  (2*B_*M_)   // 2048 columns

// workspace layout (float offsets)
#define WS_EOPE   0
#define WS_ENODE  (WS_EOPE + B_*O_)              // 16384
#define WS_PNODE  (WS_ENODE + 2*B_*M_)           // 18432
#define WS_WARC   (WS_PNODE + 2*B_*M_*C_)        // 83968
#define WS_ACC    (WS_WARC + 16)                 // 83984  (NF*NCOL = 102400 floats)

__device__ inline float rfl(float x) {
    return __int_as_float(__builtin_amdgcn_readfirstlane(__float_as_int(x)));
}

// ---------------- kernel 0: tiny precompute + ACC zeroing ----------------
__global__ void k_pre(const float* __restrict__ feat_opes,
                      const float* __restrict__ feat_mas,
                      const float* __restrict__ feat_buf,
                      const float* __restrict__ W_ope,
                      const float* __restrict__ W_mas,
                      const float* __restrict__ W_buf,
                      const float* __restrict__ W_arc_in,
                      const float* __restrict__ W_arc_out,
                      const float* __restrict__ attn_ope,
                      const float* __restrict__ attn_mas,
                      const float* __restrict__ attn_arc,
                      float* __restrict__ ws) {
    int tid = threadIdx.x;
    int bid = blockIdx.x;
    if (bid < 64) {
        // e_ope[b,o] = feat_opes[b,o,:] . (W_ope @ attn_ope)
        __shared__ float wo[INO];
        if (tid < INO) {
            float s = 0.f;
            for (int c = 0; c < C_; ++c) s += W_ope[tid*C_ + c]*attn_ope[c];
            wo[tid] = s;
        }
        __syncthreads();
        int idx = bid*256 + tid;                 // [0, 16384)
        const float* f = feat_opes + idx*INO;
        float s = 0.f;
#pragma unroll
        for (int j = 0; j < INO; ++j) s += f[j]*wo[j];
        ws[WS_EOPE + idx] = s;
    } else if (bid < 72) {
        // p_node / e_node for both branches
        int idx = (bid - 64)*256 + tid;          // [0, 2048)
        int br  = idx >> 10;
        int rem = idx & 1023;
        const float* f = (br == 0 ? feat_mas : feat_buf) + rem*INA;
        const float* W = (br == 0 ? W_mas : W_buf);
        float f8[INA];
#pragma unroll
        for (int k = 0; k < INA; ++k) f8[k] = f[k];
        float e = 0.f;
        float* pn = ws + WS_PNODE + idx*C_;
        for (int c = 0; c < C_; ++c) {
            float s = 0.f;
#pragma unroll
            for (int k = 0; k < INA; ++k) s += f8[k]*W[k*C_ + c];
            pn[c] = s;
            e += s*attn_mas[c];
        }
        ws[WS_ENODE + idx] = e;
    } else if (bid == 72) {
        // w_arc_in/out 8-vectors: W_arc @ attn_arc
        if (tid < 16) {
            const float* W = (tid < 8) ? W_arc_in : W_arc_out;
            int k = tid & 7;
            float s = 0.f;
            for (int c = 0; c < C_; ++c) s += W[k*C_ + c]*attn_arc[c];
            ws[WS_WARC + tid] = s;
        }
    } else {
        // zero the atomic accumulator region (NF*NCOL = 102400 floats, 400 blocks)
        int idx = (bid - 73)*256 + tid;
        ws[WS_ACC + idx] = 0.f;
    }
}

// ---------------- kernel A: main streaming pass ----------------
// 256 threads = 4 waves: waves 0,1 = IN stream (o halves), waves 2,3 = OUT.
// VGPR budget engineered <=64 (adjacency bitmask, SGPR uniforms) so
// __launch_bounds__(256,8) holds 8 waves/SIMD = 32 waves/CU without spills.
__global__ __launch_bounds__(256, 8) void k_main(
        const float* __restrict__ adj0, const float* __restrict__ adj1,
        const float* __restrict__ adj2, const float* __restrict__ adj3,
        const float* __restrict__ feat_opes,
        const float* __restrict__ fin_ma,  const float* __restrict__ fin_buf,
        const float* __restrict__ fout_ma, const float* __restrict__ fout_buf,
        const float* __restrict__ ws_ro,
        float* __restrict__ acc) {
    int tid = threadIdx.x;
    int m = tid & 63;
    int w = __builtin_amdgcn_readfirstlane(tid >> 6);   // 0..3, wave-uniform
    int stream = w >> 1;         // 0 = IN, 1 = OUT
    int half   = w & 1;
    int bid = blockIdx.x;
    int chunk = bid & 63;        // 64 chunks of 16 o's
    int t = bid >> 6;
    int b  = t & (B_ - 1);
    int br = t >> 4;
    int o0 = chunk*16 + half*8;  // this wave: o in [o0, o0+8)

    const float* A = stream ? (br ? adj3 : adj1) : (br ? adj2 : adj0);
    const float* F = stream ? (br ? fout_buf : fout_ma) : (br ? fin_buf : fin_ma);

    // wave-uniform weight vector -> SGPRs
    const float* wvp = ws_ro + WS_WARC + stream*8;
    float w0=rfl(wvp[0]),w1=rfl(wvp[1]),w2=rfl(wvp[2]),w3=rfl(wvp[3]);
    float w4=rfl(wvp[4]),w5=rfl(wvp[5]),w6=rfl(wvp[6]),w7=rfl(wvp[7]);

    // wave-uniform e_ope -> SGPRs
    const float* eop = ws_ro + WS_EOPE + b*O_ + o0;
    float eo[8];
#pragma unroll
    for (int i = 0; i < 8; ++i) eo[i] = rfl(eop[i]);

    float e_node_m = ws_ro[WS_ENODE + (br*B_ + b)*M_ + m];

    // adjacency -> 1-bit-per-o mask (frees 7 VGPRs vs float[8])
    const float* Ap = A + o0*M_ + m;
    unsigned amask = 0;
#pragma unroll
    for (int i = 0; i < 8; ++i) amask |= (Ap[i*M_] == 1.0f) ? (1u << i) : 0u;

    const float* P = F + ((size_t)(b*O_ + o0)*M_ + m)*INA;
    const int OSTR = M_*INA;     // 512 floats per o

    float acc_l = 0.f;
    float a8[8];                 // IN: weighted arc sum; OUT: raw arc sum
    float wiv[8];                // per-o weights, for the deferred fo pass
#pragma unroll
    for (int k = 0; k < 8; ++k) a8[k] = 0.f;

    float4 c0 = *(const float4*)(P);
    float4 c1 = *(const float4*)(P + 4);
#pragma unroll
    for (int it = 0; it < 8; ++it) {
        float4 n0, n1;
        if (it < 7) {
            n0 = *(const float4*)(P + (it+1)*OSTR);
            n1 = *(const float4*)(P + (it+1)*OSTR + 4);
        }
        float d = c0.x*w0 + c0.y*w1 + c0.z*w2 + c0.w*w3
                + c1.x*w4 + c1.y*w5 + c1.z*w6 + c1.w*w7;
        float s = eo[it] + e_node_m + d;
        s = s > 0.f ? s : SLOPE*s;
        float we = (amask & (1u << it)) ? __expf(s) : 0.f;  // plain exp: scores bounded
        wiv[it] = we; acc_l += we;
        float g = stream ? 1.0f : we;   // OUT: unweighted raw sum (reference semantics)
        a8[0] += g*c0.x; a8[1] += g*c0.y; a8[2] += g*c0.z; a8[3] += g*c0.w;
        a8[4] += g*c1.x; a8[5] += g*c1.y; a8[6] += g*c1.z; a8[7] += g*c1.w;
        c0 = n0; c1 = n1;
    }

    // deferred feat_opes-weighted sums (wave-uniform rows)
    float a16[16];
#pragma unroll
    for (int j = 0; j < 16; ++j) a16[j] = 0.f;
    const float* fo = feat_opes + (size_t)(b*O_ + o0)*INO;
#pragma unroll
    for (int it = 0; it < 8; ++it) {
        const float4* fp = (const float4*)(fo + it*INO);
        float4 f0 = fp[0], f1 = fp[1], f2 = fp[2], f3 = fp[3];
        float we = wiv[it];
        a16[0]  += we*f0.x; a16[1]  += we*f0.y; a16[2]  += we*f0.z; a16[3]  += we*f0.w;
        a16[4]  += we*f1.x; a16[5]  += we*f1.y; a16[6]  += we*f1.z; a16[7]  += we*f1.w;
        a16[8]  += we*f2.x; a16[9]  += we*f2.y; a16[10] += we*f2.z; a16[11] += we*f2.w;
        a16[12] += we*f3.x; a16[13] += we*f3.y; a16[14] += we*f3.z; a16[15] += we*f3.w;
    }

    // half==1 waves park their 25 fields in LDS; half==0 merges + atomics
    __shared__ float red[2][NFH][64];
    if (half == 1) {
        red[stream][0][m] = acc_l;
#pragma unroll
        for (int k = 0; k < 8; ++k)  red[stream][1+k][m] = a8[k];
#pragma unroll
        for (int j = 0; j < 16; ++j) red[stream][9+j][m] = a16[j];
    }
    __syncthreads();
    if (half == 0) {
        acc_l += red[stream][0][m];
#pragma unroll
        for (int k = 0; k < 8; ++k)  a8[k]  += red[stream][1+k][m];
#pragma unroll
        for (int j = 0; j < 16; ++j) a16[j] += red[stream][9+j][m];
        int col = (br*B_ + b)*M_ + m;
        int fb  = stream*NFH;
        unsafeAtomicAdd(acc + (fb + 0)*NCOL + col, acc_l);
#pragma unroll
        for (int k = 0; k < 8; ++k)
            unsafeAtomicAdd(acc + (fb + 1 + k)*NCOL + col, a8[k]);
#pragma unroll
        for (int j = 0; j < 16; ++j)
            unsafeAtomicAdd(acc + (fb + 9 + j)*NCOL + col, a16[j]);
    }
}

// ---------------- kernel B: epilogue ----------------
__global__ __launch_bounds__(64) void k_fin(
        const float* __restrict__ W_ope,
        const float* __restrict__ W_arc_in,
        const float* __restrict__ W_arc_out,
        const float* __restrict__ ws,
        float* __restrict__ out) {
    int m = threadIdx.x;         // [0,64)
    int bid = blockIdx.x;        // [0,32)
    int b  = bid & (B_ - 1);
    int br = bid >> 4;
    int col = (br*B_ + b)*M_ + m;

    __shared__ float sW[1024];   // [0..511]=W_ope, [512..767]=W_arc_in, [768..1023]=W_arc_out
    for (int i = m; i < 512; i += 64) sW[i] = W_ope[i];
    for (int i = m; i < 256; i += 64) { sW[512 + i] = W_arc_in[i]; sW[768 + i] = W_arc_out[i]; }
    __syncthreads();

    const float* acc = ws + WS_ACC;
    float v[NF];
#pragma unroll
    for (int f = 0; f < NF; ++f) v[f] = acc[f*NCOL + col];

    const float* pn = ws + WS_PNODE + col*C_;
    float pc[C_];
#pragma unroll
    for (int q = 0; q < 8; ++q) {
        float4 p4 = *(const float4*)(pn + 4*q);
        pc[4*q] = p4.x; pc[4*q+1] = p4.y; pc[4*q+2] = p4.z; pc[4*q+3] = p4.w;
    }

    float en  = ws[WS_ENODE + col];
    float ekk = 2.f*en; ekk = ekk > 0.f ? ekk : SLOPE*ekk;
    float wkk = __expf(ekk);

    float inv_i = 1.f / (v[0]  + wkk);   // l_in  + kk
    float inv_o = 1.f / (v[25] + wkk);   // l_out + kk
    float akk   = wkk*inv_i + wkk*inv_o;

    float* op = out + (size_t)col*C_;
#pragma unroll 4
    for (int c = 0; c < C_; ++c) {
        float s_ai = 0.f, s_oi = 0.f, s_ao = 0.f, s_oo = 0.f;
#pragma unroll
        for (int k = 0; k < 8; ++k) {
            s_ai += v[1+k] *sW[512 + k*C_ + c];   // ai  @ W_arc_in
            s_ao += v[26+k]*sW[768 + k*C_ + c];   // sao @ W_arc_out
        }
#pragma unroll
        for (int j = 0; j < 16; ++j) {
            float wv = sW[j*C_ + c];
            s_oi += v[9+j] *wv;                   // aoi @ W_ope
            s_oo += v[34+j]*wv;                   // aoo @ W_ope
        }
        float x = (s_ai + s_oi)*inv_i + s_ao + s_oo*inv_o + pc[c]*akk;
        op[c] = 1.f/(1.f + __expf(-x));
    }
}

extern "C" void kernel_launch(void* const* d_in, const int* in_sizes, int n_in,
                              void* d_out, int out_size, void* d_ws, size_t ws_size,
                              hipStream_t stream) {
    const float* adj0 = (const float*)d_in[0];
    const float* adj1 = (const float*)d_in[1];
    const float* adj2 = (const float*)d_in[2];
    const float* adj3 = (const float*)d_in[3];
    // d_in[4] = batch_idxes (unused by the reference)
    const float* feat_opes       = (const float*)d_in[5];
    const float* feat_mas        = (const float*)d_in[6];
    const float* feat_buf        = (const float*)d_in[7];
    const float* feat_arc_ma_in  = (const float*)d_in[8];
    const float* feat_arc_buf_in = (const float*)d_in[9];
    const float* feat_arc_ma_out = (const float*)d_in[10];
    const float* feat_arc_buf_out= (const float*)d_in[11];
    const float* W_ope    = (const float*)d_in[12];
    const float* W_mas    = (const float*)d_in[13];
    const float* W_buf    = (const float*)d_in[14];
    const float* W_arc_in = (const float*)d_in[15];
    const float* W_arc_out= (const float*)d_in[16];
    const float* attn_ope = (const float*)d_in[17];
    const float* attn_mas = (const float*)d_in[18];
    const float* attn_arc = (const float*)d_in[19];

    float* ws  = (float*)d_ws;
    float* out = (float*)d_out;

    k_pre<<<473, 256, 0, stream>>>(feat_opes, feat_mas, feat_buf,
                                   W_ope, W_mas, W_buf, W_arc_in, W_arc_out,
                                   attn_ope, attn_mas, attn_arc, ws);

    // 2048 blocks x 256 threads = 8 blocks/CU, 32 waves/CU resident
    k_main<<<2*B_*64, 256, 0, stream>>>(adj0, adj1, adj2, adj3, feat_opes,
                                        feat_arc_ma_in, feat_arc_buf_in,
                                        feat_arc_ma_out, feat_arc_buf_out,
                                        ws, ws + WS_ACC);

    k_fin<<<2*B_, 64, 0, stream>>>(W_ope, W_arc_in, W_arc_out, ws, out);
}